// Round 7
// baseline (121.143 us; speedup 1.0000x reference)
//
#include <hip/hip_runtime.h>
#include <cmath>

#define BB 2
#define SS 2048
#define EE 512
#define HH 8
#define DD 64

typedef unsigned short u16t;
typedef __bf16 bf16x8 __attribute__((ext_vector_type(8)));
typedef float f32x4 __attribute__((ext_vector_type(4)));

__device__ __forceinline__ float bf2f(u16t u){
    union{unsigned int i; float f;} c; c.i = ((unsigned int)u)<<16; return c.f;
}
__device__ __forceinline__ u16t f2bf(float x){
    union{float f; unsigned int i;} c; c.f = x;
    return (u16t)((c.i + 0x7fffu + ((c.i>>16)&1u))>>16);
}
__device__ __forceinline__ unsigned cvtpk(float a, float b){
    unsigned r;
    asm("v_cvt_pk_bf16_f32 %0, %1, %2" : "=v"(r) : "v"(a), "v"(b));
    return r;   // a -> low 16, b -> high 16 (RNE)
}
__device__ __forceinline__ float fast_tanh(float x){
    float e = __expf(2.f*x); return 1.f - 2.f/(e+1.f);
}
__device__ __forceinline__ float fast_atanh(float x){
    return 0.5f*__logf((1.f+x)/(1.f-x));
}
__device__ __forceinline__ f32x4 mfma16(bf16x8 a, bf16x8 b, f32x4 c){
    return __builtin_amdgcn_mfma_f32_16x16x32_bf16(a,b,c,0,0,0);
}
// chunk bookkeeping: QBLK=64, chunk=4 kv-tiles. qi in [0,32):
// nch(qi) = (qi>>2)+1 ; OFF(qi) = sum_{q<qi} nch(q) ; total per bh = 144
__device__ __forceinline__ int offq(int qi){
    int a = qi >> 2;
    return qi + 2*a*(a-1) + (qi&3)*a;
}

// ---------------- Kernel A: logmap0 rows (bf16 out) + W cvt, merged ------------
__global__ __launch_bounds__(256) void k_pre(const float* __restrict__ qp,
                                             const float* __restrict__ kp,
                                             const float* __restrict__ vp,
                                             u16t* __restrict__ Tlog,
                                             const float* __restrict__ Wq,
                                             const float* __restrict__ Wk,
                                             const float* __restrict__ Wv,
                                             u16t* __restrict__ Wb){
    int bx = blockIdx.x;
    if (bx < 3072){
        int gr = bx*4 + (threadIdx.x>>6);   // 0..12287
        int t = gr >> 12;
        int row = gr & 4095;
        int lane = threadIdx.x & 63;
        const float* src = (t==0 ? qp : (t==1 ? kp : vp)) + (size_t)row*EE;
        const float4* s4 = (const float4*)(src + lane*8);
        float4 a = s4[0], b = s4[1];
        float x[8] = {a.x,a.y,a.z,a.w,b.x,b.y,b.z,b.w};
        float p = 0.f;
        #pragma unroll
        for (int i=0;i<8;++i) p += x[i]*x[i];
        #pragma unroll
        for (int off=32; off>=1; off>>=1) p += __shfl_xor(p, off, 64);
        float n = sqrtf(fmaxf(p, 1e-12f));
        float f = fast_atanh(fminf(n, 1.0f-1e-5f)) / n;
        u16t yb[8];
        #pragma unroll
        for (int i=0;i<8;++i) yb[i] = f2bf(f*x[i]);
        uint4 o;
        o.x = (unsigned)yb[0] | ((unsigned)yb[1]<<16);
        o.y = (unsigned)yb[2] | ((unsigned)yb[3]<<16);
        o.z = (unsigned)yb[4] | ((unsigned)yb[5]<<16);
        o.w = (unsigned)yb[6] | ((unsigned)yb[7]<<16);
        *(uint4*)(Tlog + ((size_t)(t*4096+row)*EE + lane*8)) = o;
    } else {
        int idx = ((bx-3072)*256 + threadIdx.x)*4;     // 3*512*512 total
        int t = idx >> 18;
        int off = idx & 262143;
        const float* W = (t==0 ? Wq : (t==1 ? Wk : Wv));
        float4 a = *(const float4*)(W + off);
        uint2 o;
        o.x = (unsigned)f2bf(a.x) | ((unsigned)f2bf(a.y)<<16);
        o.y = (unsigned)f2bf(a.z) | ((unsigned)f2bf(a.w)<<16);
        *(uint2*)(Wb + idx) = o;
    }
}

// ---------------- Kernel B: fused projection GEMM + expmap0 + head split -------
// Block owns full rows: M=64, N=512 (4 waves x 128-col stripes), K=512 in 8
// steps of 64. W staged in LDS (register-prefetched); A (Tlog) direct-global
// with register prefetch. Epilogue: row-norm (shfl + LDS cross-wave), expmap0,
// per-head norms from bf16-rounded values, writes Q/K/VT + qn2/kn2/lam1.
__global__ __launch_bounds__(256,1) void k_projexp(const u16t* __restrict__ Tlog,
        const u16t* __restrict__ Wb,
        const float* __restrict__ bq, const float* __restrict__ bk,
        const float* __restrict__ bv,
        u16t* __restrict__ Q, u16t* __restrict__ K, u16t* __restrict__ VT,
        float* __restrict__ qn2, float* __restrict__ kn2,
        float* __restrict__ lam1){
    __shared__ __align__(16) u16t Wl[512][72];   // 73,728 B
    __shared__ float nsum[64][4];
    int bx = blockIdx.x;                 // 3 t x 64 m-blocks
    int t = bx >> 6; int m0 = (bx & 63) << 6;
    int tid = threadIdx.x; int wv = tid>>6; int lane = tid&63;
    int l15 = lane & 15; int l4 = lane >> 4;
    const u16t* Tt = Tlog + (size_t)t*4096*EE;
    const u16t* Wt = Wb + (size_t)t*EE*EE;
    const float* bias = (t==0 ? bq : (t==1 ? bk : bv));
    int n0 = wv << 7;                    // wave's 128-col stripe
    int srow = tid >> 3;                 // staging: row
    int schk = tid & 7;                  // staging: 16B chunk
    f32x4 z4 = {0.f,0.f,0.f,0.f};
    f32x4 acc[4][8];
    #pragma unroll
    for (int m=0;m<4;++m)
        #pragma unroll
        for (int f=0;f<8;++f) acc[m][f] = z4;
    // prologue prefetch: W k-step 0 + A k-step 0
    uint4 wpf[16];
    #pragma unroll
    for (int p=0; p<16; ++p)
        wpf[p] = *(const uint4*)(Wt + (size_t)(p*32 + srow)*EE + schk*8);
    bf16x8 pa0[4], pa1[4];
    #pragma unroll
    for (int m=0;m<4;++m){
        pa0[m] = *(const bf16x8*)(Tt + (size_t)(m0+m*16+l15)*EE + l4*8);
        pa1[m] = *(const bf16x8*)(Tt + (size_t)(m0+m*16+l15)*EE + 32 + l4*8);
    }
    for (int ks=0; ks<8; ++ks){
        #pragma unroll
        for (int p=0; p<16; ++p)
            *(uint4*)&Wl[p*32 + srow][schk*8] = wpf[p];
        __syncthreads();
        bf16x8 a0[4], a1[4];
        #pragma unroll
        for (int m=0;m<4;++m){ a0[m] = pa0[m]; a1[m] = pa1[m]; }
        if (ks < 7){
            int kn = (ks+1)*64;
            #pragma unroll
            for (int p=0; p<16; ++p)
                wpf[p] = *(const uint4*)(Wt + (size_t)(p*32 + srow)*EE + kn + schk*8);
            #pragma unroll
            for (int m=0;m<4;++m){
                pa0[m] = *(const bf16x8*)(Tt + (size_t)(m0+m*16+l15)*EE + kn + l4*8);
                pa1[m] = *(const bf16x8*)(Tt + (size_t)(m0+m*16+l15)*EE + kn + 32 + l4*8);
            }
        }
        #pragma unroll
        for (int f=0; f<8; ++f){
            bf16x8 b0 = *(const bf16x8*)&Wl[n0 + f*16 + l15][l4*8];
            bf16x8 b1 = *(const bf16x8*)&Wl[n0 + f*16 + l15][32 + l4*8];
            #pragma unroll
            for (int m=0;m<4;++m){
                acc[m][f] = mfma16(a0[m], b0, acc[m][f]);
                acc[m][f] = mfma16(a1[m], b1, acc[m][f]);
            }
        }
        __syncthreads();
    }
    // bias
    float biasv[8];
    #pragma unroll
    for (int f=0; f<8; ++f) biasv[f] = bias[n0 + f*16 + l15];
    #pragma unroll
    for (int m=0;m<4;++m)
        #pragma unroll
        for (int f=0; f<8; ++f)
            #pragma unroll
            for (int r=0;r<4;++r) acc[m][f][r] += biasv[f];
    // row norms (over all 512 cols): shfl over l15, cross-wave via LDS
    #pragma unroll
    for (int m=0;m<4;++m){
        #pragma unroll
        for (int r=0;r<4;++r){
            float p = 0.f;
            #pragma unroll
            for (int f=0; f<8; ++f) p += acc[m][f][r]*acc[m][f][r];
            p += __shfl_xor(p,1,64); p += __shfl_xor(p,2,64);
            p += __shfl_xor(p,4,64); p += __shfl_xor(p,8,64);
            if (l15 == 0) nsum[m*16 + l4*4 + r][wv] = p;
        }
    }
    __syncthreads();
    // expmap0 + head split + per-head norms (from bf16-rounded values)
    #pragma unroll
    for (int m=0;m<4;++m){
        #pragma unroll
        for (int r=0;r<4;++r){
            int rowib = m*16 + l4*4 + r;
            float4 n4 = *(const float4*)&nsum[rowib][0];
            float np2 = (n4.x+n4.y)+(n4.z+n4.w);
            float n = sqrtf(fmaxf(np2, 1e-12f));
            float fsc = fast_tanh(n)/n;
            u16t yb[8]; float hpA=0.f, hpB=0.f;
            #pragma unroll
            for (int f=0; f<8; ++f){
                float y = fsc*acc[m][f][r];
                u16t bb = f2bf(y);
                yb[f] = bb;
                float yr = bf2f(bb);
                if (f<4) hpA += yr*yr; else hpB += yr*yr;
            }
            hpA += __shfl_xor(hpA,1,64); hpA += __shfl_xor(hpA,2,64);
            hpA += __shfl_xor(hpA,4,64); hpA += __shfl_xor(hpA,8,64);
            hpB += __shfl_xor(hpB,1,64); hpB += __shfl_xor(hpB,2,64);
            hpB += __shfl_xor(hpB,4,64); hpB += __shfl_xor(hpB,8,64);
            hpA = fminf(hpA, 0.99999988f);
            hpB = fminf(hpB, 0.99999988f);
            int grow = m0 + rowib;
            int b_ = grow >> 11; int s = grow & 2047;
            int h0 = wv*2;
            size_t ihA = ((size_t)(b_*HH + h0))*SS + s;
            size_t ihB = ihA + SS;
            if (t == 0){
                #pragma unroll
                for (int f=0; f<4; ++f){
                    Q[ihA*DD + f*16 + l15] = yb[f];
                    Q[ihB*DD + f*16 + l15] = yb[f+4];
                }
                if (l15 == 0){ qn2[ihA] = hpA; qn2[ihB] = hpB; }
            } else if (t == 1){
                #pragma unroll
                for (int f=0; f<4; ++f){
                    K[ihA*DD + f*16 + l15] = yb[f];
                    K[ihB*DD + f*16 + l15] = yb[f+4];
                }
                if (l15 == 0){ kn2[ihA] = hpA; kn2[ihB] = hpB; }
            } else {
                float lamA = 2.f / fmaxf(1.f - hpA, 1e-6f);
                float lamB = 2.f / fmaxf(1.f - hpB, 1e-6f);
                size_t vbase = (size_t)(b_*HH + h0)*DD;
                #pragma unroll
                for (int f=0; f<4; ++f){
                    VT[(vbase + f*16 + l15)*SS + s]      = f2bf(bf2f(yb[f])*lamA);
                    VT[(vbase + DD + f*16 + l15)*SS + s] = f2bf(bf2f(yb[f+4])*lamB);
                }
                if (l15 == 0){ lam1[ihA] = lamA - 1.f; lam1[ihB] = lamB - 1.f; }
            }
        }
    }
}

// ---------------- Kernel D: fused causal hyperbolic attention ------------------
// QBLK=64 (4 waves x 16q), KVBLK=64, chunk=4. Swapped-operand MFMAs; w packed
// via v_cvt_pk_bf16_f32; fast path w=rcp(zz) when tau'==1 && gamma==0 (exact:
// exp(-1*dist+0) == 1/zz), general log/exp path otherwise.
#define EW_BLOCK(DO_DIAG, FASTW)                                              \
    _Pragma("unroll")                                                         \
    for (int f=0; f<4; ++f){                                                  \
        float4 kn24 = *(const float4*)&kn2s[f*16 + l4*4];                     \
        float4 akf4 = *(const float4*)&akfs[f*16 + l4*4];                     \
        float4 l14  = *(const float4*)&l1s [f*16 + l4*4];                     \
        float wv4[4];                                                         \
        _Pragma("unroll")                                                     \
        for (int r=0; r<4; ++r){                                              \
            float sq  = fmaxf(fmaf(-2.f, c[f][r], qv + ((const float*)&kn24)[r]), 0.f); \
            float co  = fminf(aq2 * ((const float*)&akf4)[r], 2e6f);          \
            float rho = sq * co;                                              \
            float tt  = fmaf(rho, rho, rho + rho);                            \
            float zz  = 1.f + rho + __builtin_amdgcn_sqrtf(tt);               \
            float w;                                                          \
            if (FASTW){ w = __builtin_amdgcn_rcpf(zz); }                      \
            else { float L = __builtin_amdgcn_logf(zz);                       \
                   w = __builtin_amdgcn_exp2f(fmaf(-tauexp, L, gm2)); }       \
            if (DO_DIAG && (kv0 + f*16 + l4*4 + r) > qrow) w = 0.f;           \
            dn = fmaf(w, ((const float*)&l14)[r], dn);                        \
            wv4[r] = w;                                                       \
        }                                                                     \
        uint2 u2; u2.x = cvtpk(wv4[0], wv4[1]); u2.y = cvtpk(wv4[2], wv4[3]); \
        *(uint2*)&Wt[16*wv + l15][f*16 + l4*4] = u2;                          \
    }

__global__ __launch_bounds__(256,5) void k_attn(const u16t* __restrict__ Q,
        const u16t* __restrict__ K, const u16t* __restrict__ VT,
        const float* __restrict__ qn2, const float* __restrict__ kn2,
        const float* __restrict__ lam1, const float* __restrict__ taup,
        const float* __restrict__ gammap,
        float* __restrict__ pnum, float* __restrict__ pden){
    __shared__ __align__(16) u16t Kt[64][72];
    __shared__ __align__(16) u16t Vt[64][72];   // V^T tile: [d][kv]
    __shared__ __align__(16) u16t Wt[64][72];   // w[q][kv], per-wave row stripes
    __shared__ float kn2s[64], akfs[64], l1s[64];
    int bx = blockIdx.x;
    int bh = bx & 15;               // low bits -> per-bh XCD/L2 affinity
    int u = bx >> 4;                // 0..143
    int v = 143 - u;                // heavy qi first
    int qi = 31;
    while (offq(qi) > v) --qi;
    int c0 = v - offq(qi);
    int jt0 = c0 << 2;
    int jt1 = min(jt0 + 4, qi + 1);
    int s0 = qi << 6;
    int tid = threadIdx.x; int wv = tid>>6; int lane = tid&63;
    int l15 = lane & 15; int l4 = lane >> 4;
    float tauexp = __expf(taup[0]);
    float gm2 = gammap[0] * 1.44269504088896340736f;  // gamma * log2(e)
    bool fastw = (tauexp == 1.0f) && (gm2 == 0.0f);
    size_t base = (size_t)bh * SS;
    int qrow = s0 + 16*wv + l15;    // this lane's global q row
    bf16x8 aQ0 = *(const bf16x8*)(Q + (base + qrow)*DD + l4*8);
    bf16x8 aQ1 = *(const bf16x8*)(Q + (base + qrow)*DD + 32 + l4*8);
    float qv  = qn2[base + qrow];
    float aq2 = 2.f * __builtin_amdgcn_rcpf(fmaxf(1.f - qv, 1e-6f));
    f32x4 z4 = {0.f,0.f,0.f,0.f};
    f32x4 num[4] = {z4,z4,z4,z4};
    float dn = 0.f;
    int rr = tid >> 2; int cc = (tid & 3) << 4;
    // register prefetch (T14)
    uint4 pka0, pka1, pva0, pva1; float pkn = 0.f, pl1 = 0.f;
    {   // prologue: load tile jt0
        int kv0 = jt0 << 6;
        const uint4* gk = (const uint4*)(K + (base + kv0 + rr)*DD + cc);
        pka0 = gk[0]; pka1 = gk[1];
        const uint4* gv = (const uint4*)(VT + ((size_t)bh*DD + rr)*SS + kv0 + cc);
        pva0 = gv[0]; pva1 = gv[1];
        if (tid < 64){ pkn = kn2[base+kv0+tid]; pl1 = lam1[base+kv0+tid]; }
    }
    for (int jt=jt0; jt<jt1; ++jt){
        // commit prefetched tile to LDS
        *(uint4*)&Kt[rr][cc]   = pka0;
        *(uint4*)&Kt[rr][cc+8] = pka1;
        *(uint4*)&Vt[rr][cc]   = pva0;
        *(uint4*)&Vt[rr][cc+8] = pva1;
        if (tid < 64){
            kn2s[tid] = pkn;
            l1s[tid]  = pl1;
            akfs[tid] = __builtin_amdgcn_rcpf(fmaxf(1.f - pkn, 1e-6f));
        }
        __syncthreads();
        // issue next tile's global loads (overlap with compute below)
        if (jt+1 < jt1){
            int kv0n = (jt+1) << 6;
            const uint4* gk = (const uint4*)(K + (base + kv0n + rr)*DD + cc);
            pka0 = gk[0]; pka1 = gk[1];
            const uint4* gv = (const uint4*)(VT + ((size_t)bh*DD + rr)*SS + kv0n + cc);
            pva0 = gv[0]; pva1 = gv[1];
            if (tid < 64){ pkn = kn2[base+kv0n+tid]; pl1 = lam1[base+kv0n+tid]; }
        }
        int kv0 = jt << 6;
        // QK^T swapped: c[f][r] = dot(q=l15, k=16f+4l4+r)
        f32x4 c[4] = {z4,z4,z4,z4};
        #pragma unroll
        for (int f=0; f<4; ++f){
            bf16x8 kb0 = *(const bf16x8*)&Kt[f*16+l15][l4*8];
            bf16x8 kb1 = *(const bf16x8*)&Kt[f*16+l15][32+l4*8];
            c[f] = mfma16(kb0, aQ0, c[f]);
            c[f] = mfma16(kb1, aQ1, c[f]);
        }
        // elementwise distance -> w, packed to Wt
        if (jt == qi){
            if (fastw) { EW_BLOCK(true, true) } else { EW_BLOCK(true, false) }
        } else {
            if (fastw) { EW_BLOCK(false, true) } else { EW_BLOCK(false, false) }
        }
        // PV swapped: num[f][r] = M[q=l15][d=16f+4l4+r]
        bf16x8 pw0 = *(const bf16x8*)&Wt[16*wv + l15][l4*8];
        bf16x8 pw1 = *(const bf16x8*)&Wt[16*wv + l15][32 + l4*8];
        #pragma unroll
        for (int f=0; f<4; ++f){
            bf16x8 vb0 = *(const bf16x8*)&Vt[f*16+l15][l4*8];
            bf16x8 vb1 = *(const bf16x8*)&Vt[f*16+l15][32+l4*8];
            num[f] = mfma16(vb0, pw0, num[f]);
            num[f] = mfma16(vb1, pw1, num[f]);
        }
        __syncthreads();
    }
    // den: reduce over the 16 k's held per lane -> over l4 groups
    dn += __shfl_xor(dn, 16, 64);
    dn += __shfl_xor(dn, 32, 64);
    // store partials: pn[q][d] with d-consecutive float4
    size_t pidx = (size_t)bh*144 + offq(qi) + c0;
    float* pn = pnum + pidx*4096;
    #pragma unroll
    for (int f=0; f<4; ++f)
        *(f32x4*)&pn[(16*wv + l15)*64 + f*16 + l4*4] = num[f];
    if (l4 == 0) pden[pidx*64 + 16*wv + l15] = dn;
}

// ---------------- Kernel E: combine partials + gyromidpoint + logmap + expmap --
// block = (b, 16-row s-tile); thread = (row, head, half): tid = row*16 + h*2 + half
__global__ __launch_bounds__(256) void k_post(const float* __restrict__ pnum,
        const float* __restrict__ pden, float* __restrict__ out, float beta){
    int bx = blockIdx.x;              // 2 b x 128 s-tiles
    int b = bx >> 7; int stile = bx & 127;
    int tid = threadIdx.x;
    int row = tid >> 4; int h = (tid >> 1) & 7; int half = tid & 1;
    int s = stile*16 + row;
    int qi = s >> 6; int rowin = s & 63;
    int nch = (qi >> 2) + 1;
    size_t pb = (size_t)(b*HH + h)*144 + offq(qi);
    float mv[32];
    #pragma unroll
    for (int i=0;i<32;++i) mv[i] = 0.f;
    float den = 0.f;
    for (int cc=0; cc<nch; ++cc){
        const float* pn = pnum + (pb+cc)*4096 + rowin*64 + half*32;
        #pragma unroll
        for (int i=0;i<8;++i){
            float4 v = *(const float4*)(pn + i*4);
            mv[i*4+0]+=v.x; mv[i*4+1]+=v.y; mv[i*4+2]+=v.z; mv[i*4+3]+=v.w;
        }
        den += pden[(pb+cc)*64 + rowin];
    }
    float invd = 1.f / fmaxf(den, 1e-6f);
    float mn2h = 0.f;
    #pragma unroll
    for (int i=0;i<32;++i){ mv[i] *= invd; mn2h += mv[i]*mv[i]; }
    // per-head norm over 64 dims: pair (half) reduce
    float mn2 = mn2h + __shfl_xor(mn2h, 1, 64);
    float mn = sqrtf(fmaxf(mn2, 1e-12f));
    float g = beta * 0.5f * fast_atanh(fminf(mn, 1.0f-1e-5f)) / mn;   // t_h = g*m_h
    // E-norm^2 = sum_h g^2*mn2 : reduce over h bits (1,2,3 of tid>>1)
    float tn = g*g*mn2;
    tn += __shfl_xor(tn, 2, 64);
    tn += __shfl_xor(tn, 4, 64);
    tn += __shfl_xor(tn, 8, 64);
    float en = sqrtf(fmaxf(tn, 1e-12f));
    float f = fast_tanh(en)/en;
    float gf = g * f;
    float* dst = out + ((size_t)(b*SS + s))*EE + h*DD + half*32;
    #pragma unroll
    for (int i=0;i<8;++i){
        float4 v = {gf*mv[i*4+0], gf*mv[i*4+1], gf*mv[i*4+2], gf*mv[i*4+3]};
        *(float4*)(dst + i*4) = v;
    }
}

extern "C" void kernel_launch(void* const* d_in, const int* in_sizes, int n_in,
                              void* d_out, int out_size, void* d_ws, size_t ws_size,
                              hipStream_t stream) {
    const float* q_in  = (const float*)d_in[0];
    const float* k_in  = (const float*)d_in[1];
    const float* v_in  = (const float*)d_in[2];
    const float* Wq    = (const float*)d_in[3];
    const float* Wk    = (const float*)d_in[4];
    const float* Wv    = (const float*)d_in[5];
    const float* bq    = (const float*)d_in[6];
    const float* bk    = (const float*)d_in[7];
    const float* bv    = (const float*)d_in[8];
    const float* tau   = (const float*)d_in[9];
    const float* gamma = (const float*)d_in[10];
    float* out = (float*)d_out;

    char* ws = (char*)d_ws;
    u16t*  Tlog = (u16t*)(ws + 0);            // 12,582,912 B
    u16t*  Wb   = (u16t*)(ws + 12582912);     //  1,572,864 B
    u16t*  Qb   = (u16t*)(ws + 26738688);     //  4,194,304 B
    u16t*  Kb   = (u16t*)(ws + 30932992);     //  4,194,304 B
    u16t*  VTb  = (u16t*)(ws + 35127296);     //  4,194,304 B  (V^T * lambda)
    float* qn2  = (float*)(ws + 39321600);    //    131,072 B
    float* kn2  = (float*)(ws + 39452672);    //    131,072 B
    float* lam1 = (float*)(ws + 39583744);    //    131,072 B
    float* pnum = (float*)(ws + 39714816);    // 16*144*4096*4 = 37,748,736 B
    float* pden = (float*)(ws + 77463552);    // 16*144*64*4   =    589,824 B

    // beta-concatenation ratio: exp(lbeta(E/2,1/2) - lbeta(D/2,1/2))
    double lb1 = std::lgamma(256.0) + std::lgamma(0.5) - std::lgamma(256.5);
    double lb2 = std::lgamma(32.0)  + std::lgamma(0.5) - std::lgamma(32.5);
    float beta = (float)std::exp(lb1 - lb2);

    k_pre<<<3840, 256, 0, stream>>>(q_in, k_in, v_in, Tlog, Wq, Wk, Wv, Wb);
    k_projexp<<<192, 256, 0, stream>>>(Tlog, Wb, bq, bk, bv,
                                       Qb, Kb, VTb, qn2, kn2, lam1);
    k_attn<<<2304, 256, 0, stream>>>(Qb, Kb, VTb, qn2, kn2, lam1, tau, gamma,
                                     pnum, pden);
    k_post<<<256, 256, 0, stream>>>(pnum, pden, out, beta);
}

// Round 8
// 95.528 us; speedup vs baseline: 1.2681x; 1.2681x over previous
//
#include <hip/hip_runtime.h>
#include <cmath>

#define BB 2
#define SS 2048
#define EE 512
#define HH 8
#define DD 64

typedef unsigned short u16t;
typedef __bf16 bf16x8 __attribute__((ext_vector_type(8)));
typedef float f32x4 __attribute__((ext_vector_type(4)));

__device__ __forceinline__ float bf2f(u16t u){
    union{unsigned int i; float f;} c; c.i = ((unsigned int)u)<<16; return c.f;
}
__device__ __forceinline__ u16t f2bf(float x){
    union{float f; unsigned int i;} c; c.f = x;
    return (u16t)((c.i + 0x7fffu + ((c.i>>16)&1u))>>16);
}
__device__ __forceinline__ unsigned cvtpk(float a, float b){
    unsigned r;
    asm("v_cvt_pk_bf16_f32 %0, %1, %2" : "=v"(r) : "v"(a), "v"(b));
    return r;   // a -> low 16, b -> high 16 (RNE)
}
__device__ __forceinline__ float fast_tanh(float x){
    float e = __expf(2.f*x); return 1.f - 2.f/(e+1.f);
}
__device__ __forceinline__ float fast_atanh(float x){
    return 0.5f*__logf((1.f+x)/(1.f-x));
}
__device__ __forceinline__ f32x4 mfma16(bf16x8 a, bf16x8 b, f32x4 c){
    return __builtin_amdgcn_mfma_f32_16x16x32_bf16(a,b,c,0,0,0);
}
// chunk bookkeeping: QBLK=64, chunk=4 kv-tiles. qi in [0,32):
// nch(qi) = (qi>>2)+1 ; OFF(qi) = sum_{q<qi} nch(q) ; total per bh = 144
__device__ __forceinline__ int offq(int qi){
    int a = qi >> 2;
    return qi + 2*a*(a-1) + (qi&3)*a;
}

// ---------------- Kernel A: logmap0 rows (bf16 out) + W cvt, merged ------------
__global__ __launch_bounds__(256) void k_pre(const float* __restrict__ qp,
                                             const float* __restrict__ kp,
                                             const float* __restrict__ vp,
                                             u16t* __restrict__ Tlog,
                                             const float* __restrict__ Wq,
                                             const float* __restrict__ Wk,
                                             const float* __restrict__ Wv,
                                             u16t* __restrict__ Wb){
    int bx = blockIdx.x;
    if (bx < 3072){
        int gr = bx*4 + (threadIdx.x>>6);   // 0..12287
        int t = gr >> 12;
        int row = gr & 4095;
        int lane = threadIdx.x & 63;
        const float* src = (t==0 ? qp : (t==1 ? kp : vp)) + (size_t)row*EE;
        const float4* s4 = (const float4*)(src + lane*8);
        float4 a = s4[0], b = s4[1];
        float x[8] = {a.x,a.y,a.z,a.w,b.x,b.y,b.z,b.w};
        float p = 0.f;
        #pragma unroll
        for (int i=0;i<8;++i) p += x[i]*x[i];
        #pragma unroll
        for (int off=32; off>=1; off>>=1) p += __shfl_xor(p, off, 64);
        float n = sqrtf(fmaxf(p, 1e-12f));
        float f = fast_atanh(fminf(n, 1.0f-1e-5f)) / n;
        u16t yb[8];
        #pragma unroll
        for (int i=0;i<8;++i) yb[i] = f2bf(f*x[i]);
        uint4 o;
        o.x = (unsigned)yb[0] | ((unsigned)yb[1]<<16);
        o.y = (unsigned)yb[2] | ((unsigned)yb[3]<<16);
        o.z = (unsigned)yb[4] | ((unsigned)yb[5]<<16);
        o.w = (unsigned)yb[6] | ((unsigned)yb[7]<<16);
        *(uint4*)(Tlog + ((size_t)(t*4096+row)*EE + lane*8)) = o;
    } else {
        int idx = ((bx-3072)*256 + threadIdx.x)*4;     // 3*512*512 total
        int t = idx >> 18;
        int off = idx & 262143;
        const float* W = (t==0 ? Wq : (t==1 ? Wk : Wv));
        float4 a = *(const float4*)(W + off);
        uint2 o;
        o.x = (unsigned)f2bf(a.x) | ((unsigned)f2bf(a.y)<<16);
        o.y = (unsigned)f2bf(a.z) | ((unsigned)f2bf(a.w)<<16);
        *(uint2*)(Wb + idx) = o;
    }
}

// ---------------- Kernel B: U = Tlog @ W^T + b (MFMA GEMM, bf16 out) -----------
__global__ __launch_bounds__(256) void k_proj(const u16t* __restrict__ Tlog,
                                              const u16t* __restrict__ Wb,
                                              const float* __restrict__ bq,
                                              const float* __restrict__ bk,
                                              const float* __restrict__ bv,
                                              u16t* __restrict__ U){
    __shared__ __align__(16) u16t Wl[64][72];
    int bx = blockIdx.x;                 // 3 * 64 * 8
    int t = bx >> 9; int rem = bx & 511;
    int m0 = (rem >> 3) << 6; int n0 = (rem & 7) << 6;
    int tid = threadIdx.x; int wv = tid>>6; int lane = tid&63;
    int l15 = lane & 15; int l4 = lane >> 4;
    const u16t* Tt = Tlog + (size_t)t*4096*EE;
    const u16t* Wt = Wb + (size_t)t*EE*EE;
    const float* bias = (t==0 ? bq : (t==1 ? bk : bv));
    f32x4 z = {0.f,0.f,0.f,0.f};
    f32x4 acc[4] = {z,z,z,z};
    int arow = m0 + 16*wv + l15;
    int rr = tid >> 2; int cc = (tid & 3) * 16;
    uint4 w0, w1;
    {   // prologue: W-tile ks=0
        const uint4* g = (const uint4*)(Wt + (size_t)(n0+rr)*EE + cc);
        w0 = g[0]; w1 = g[1];
    }
    for (int ks=0; ks<8; ++ks){
        int k0 = ks*64;
        *(uint4*)&Wl[rr][cc]   = w0;
        *(uint4*)&Wl[rr][cc+8] = w1;
        __syncthreads();
        if (ks < 7){
            const uint4* g = (const uint4*)(Wt + (size_t)(n0+rr)*EE + k0 + 64 + cc);
            w0 = g[0]; w1 = g[1];
        }
        bf16x8 a0 = *(const bf16x8*)(Tt + (size_t)arow*EE + k0 + l4*8);
        bf16x8 a1 = *(const bf16x8*)(Tt + (size_t)arow*EE + k0 + 32 + l4*8);
        #pragma unroll
        for (int f=0; f<4; ++f){
            bf16x8 b0 = *(const bf16x8*)&Wl[f*16+l15][l4*8];
            bf16x8 b1 = *(const bf16x8*)&Wl[f*16+l15][32+l4*8];
            acc[f] = mfma16(a0, b0, acc[f]);
            acc[f] = mfma16(a1, b1, acc[f]);
        }
        __syncthreads();
    }
    u16t* Ut = U + (size_t)t*4096*EE;
    #pragma unroll
    for (int f=0; f<4; ++f){
        int col = n0 + f*16 + l15;
        float bs = bias[col];
        #pragma unroll
        for (int r=0; r<4; ++r){
            int row = m0 + 16*wv + l4*4 + r;
            Ut[(size_t)row*EE + col] = f2bf(acc[f][r] + bs);
        }
    }
}

// ---------------- Kernel C: expmap0 + head split + norms (V stored transposed) --
__global__ __launch_bounds__(256) void k_expmap_split(const u16t* __restrict__ U,
        u16t* __restrict__ Q, u16t* __restrict__ K, u16t* __restrict__ VT,
        float* __restrict__ qn2, float* __restrict__ kn2, float* __restrict__ lam1){
    int gr = blockIdx.x*4 + (threadIdx.x>>6);   // 0..12287
    int t = gr >> 12;
    int row = gr & 4095;
    int b = row >> 11; int s = row & 2047;
    int lane = threadIdx.x & 63;
    const u16t* u = U + ((size_t)t*4096 + row)*EE;
    uint4 raw = *(const uint4*)(u + lane*8);
    const u16t* rs = (const u16t*)&raw;
    float x[8];
    #pragma unroll
    for (int i=0;i<8;++i) x[i] = bf2f(rs[i]);
    float p = 0.f;
    #pragma unroll
    for (int i=0;i<8;++i) p += x[i]*x[i];
    #pragma unroll
    for (int off=32; off>=1; off>>=1) p += __shfl_xor(p, off, 64);
    float n = sqrtf(fmaxf(p, 1e-12f));
    float f = fast_tanh(n)/n;
    float y[8]; u16t yb[8];
    float hp = 0.f;
    #pragma unroll
    for (int i=0;i<8;++i){
        yb[i] = f2bf(f*x[i]);
        y[i]  = bf2f(yb[i]);        // rounded values -> consistent norms
        hp += y[i]*y[i];
    }
    #pragma unroll
    for (int off=1; off<8; off<<=1) hp += __shfl_xor(hp, off, 64);
    hp = fminf(hp, 0.99999988f);    // guard: keep strictly below 1 for rcp path
    int h = lane >> 3;
    size_t ih = (size_t)(b*HH + h)*SS + s;
    if (t == 0){
        uint4 o;
        o.x=(unsigned)yb[0]|((unsigned)yb[1]<<16); o.y=(unsigned)yb[2]|((unsigned)yb[3]<<16);
        o.z=(unsigned)yb[4]|((unsigned)yb[5]<<16); o.w=(unsigned)yb[6]|((unsigned)yb[7]<<16);
        *(uint4*)(Q + ih*DD + (lane&7)*8) = o;
        if ((lane&7)==0) qn2[ih] = hp;
    } else if (t == 1){
        uint4 o;
        o.x=(unsigned)yb[0]|((unsigned)yb[1]<<16); o.y=(unsigned)yb[2]|((unsigned)yb[3]<<16);
        o.z=(unsigned)yb[4]|((unsigned)yb[5]<<16); o.w=(unsigned)yb[6]|((unsigned)yb[7]<<16);
        *(uint4*)(K + ih*DD + (lane&7)*8) = o;
        if ((lane&7)==0) kn2[ih] = hp;
    } else {
        float lam = 2.f / fmaxf(1.f - hp, 1e-6f);
        size_t bh = (size_t)(b*HH + h);
        int d0 = (lane&7)*8;
        #pragma unroll
        for (int i=0;i<8;++i)
            VT[(bh*DD + d0 + i)*SS + s] = f2bf(y[i]*lam);   // V^T, scaled by lambda
        if ((lane&7)==0) lam1[ih] = lam - 1.f;
    }
}

// ---------------- Kernel D: fused causal hyperbolic attention ------------------
// QBLK=64 (4 waves x 16q), KVBLK=64, chunk=4. Swapped-operand MFMAs; w packed
// via v_cvt_pk_bf16_f32; fast path w=rcp(zz) when tau'==1 && gamma==0 (exact:
// exp(-1*dist+0) == 1/zz), general log/exp path otherwise.
#define EW_BLOCK(DO_DIAG, FASTW)                                              \
    _Pragma("unroll")                                                         \
    for (int f=0; f<4; ++f){                                                  \
        float4 kn24 = *(const float4*)&kn2s[f*16 + l4*4];                     \
        float4 akf4 = *(const float4*)&akfs[f*16 + l4*4];                     \
        float4 l14  = *(const float4*)&l1s [f*16 + l4*4];                     \
        float wv4[4];                                                         \
        _Pragma("unroll")                                                     \
        for (int r=0; r<4; ++r){                                              \
            float sq  = fmaxf(fmaf(-2.f, c[f][r], qv + ((const float*)&kn24)[r]), 0.f); \
            float co  = fminf(aq2 * ((const float*)&akf4)[r], 2e6f);          \
            float rho = sq * co;                                              \
            float tt  = fmaf(rho, rho, rho + rho);                            \
            float zz  = 1.f + rho + __builtin_amdgcn_sqrtf(tt);               \
            float w;                                                          \
            if (FASTW){ w = __builtin_amdgcn_rcpf(zz); }                      \
            else { float L = __builtin_amdgcn_logf(zz);                       \
                   w = __builtin_amdgcn_exp2f(fmaf(-tauexp, L, gm2)); }       \
            if (DO_DIAG && (kv0 + f*16 + l4*4 + r) > qrow) w = 0.f;           \
            dn = fmaf(w, ((const float*)&l14)[r], dn);                        \
            wv4[r] = w;                                                       \
        }                                                                     \
        uint2 u2; u2.x = cvtpk(wv4[0], wv4[1]); u2.y = cvtpk(wv4[2], wv4[3]); \
        *(uint2*)&Wt[16*wv + l15][f*16 + l4*4] = u2;                          \
    }

__global__ __launch_bounds__(256,5) void k_attn(const u16t* __restrict__ Q,
        const u16t* __restrict__ K, const u16t* __restrict__ VT,
        const float* __restrict__ qn2, const float* __restrict__ kn2,
        const float* __restrict__ lam1, const float* __restrict__ taup,
        const float* __restrict__ gammap,
        float* __restrict__ pnum, float* __restrict__ pden){
    __shared__ __align__(16) u16t Kt[64][72];
    __shared__ __align__(16) u16t Vt[64][72];   // V^T tile: [d][kv]
    __shared__ __align__(16) u16t Wt[64][72];   // w[q][kv], per-wave row stripes
    __shared__ float kn2s[64], akfs[64], l1s[64];
    int bx = blockIdx.x;
    int bh = bx & 15;               // low bits -> per-bh XCD/L2 affinity
    int u = bx >> 4;                // 0..143
    int v = 143 - u;                // heavy qi first
    int qi = 31;
    while (offq(qi) > v) --qi;
    int c0 = v - offq(qi);
    int jt0 = c0 << 2;
    int jt1 = min(jt0 + 4, qi + 1);
    int s0 = qi << 6;
    int tid = threadIdx.x; int wv = tid>>6; int lane = tid&63;
    int l15 = lane & 15; int l4 = lane >> 4;
    float tauexp = __expf(taup[0]);
    float gm2 = gammap[0] * 1.44269504088896340736f;  // gamma * log2(e)
    bool fastw = (tauexp == 1.0f) && (gm2 == 0.0f);
    size_t base = (size_t)bh * SS;
    int qrow = s0 + 16*wv + l15;    // this lane's global q row
    bf16x8 aQ0 = *(const bf16x8*)(Q + (base + qrow)*DD + l4*8);
    bf16x8 aQ1 = *(const bf16x8*)(Q + (base + qrow)*DD + 32 + l4*8);
    float qv  = qn2[base + qrow];
    float aq2 = 2.f * __builtin_amdgcn_rcpf(fmaxf(1.f - qv, 1e-6f));
    f32x4 z4 = {0.f,0.f,0.f,0.f};
    f32x4 num[4] = {z4,z4,z4,z4};
    float dn = 0.f;
    int rr = tid >> 2; int cc = (tid & 3) << 4;
    // register prefetch (T14)
    uint4 pka0, pka1, pva0, pva1; float pkn = 0.f, pl1 = 0.f;
    {   // prologue: load tile jt0
        int kv0 = jt0 << 6;
        const uint4* gk = (const uint4*)(K + (base + kv0 + rr)*DD + cc);
        pka0 = gk[0]; pka1 = gk[1];
        const uint4* gv = (const uint4*)(VT + ((size_t)bh*DD + rr)*SS + kv0 + cc);
        pva0 = gv[0]; pva1 = gv[1];
        if (tid < 64){ pkn = kn2[base+kv0+tid]; pl1 = lam1[base+kv0+tid]; }
    }
    for (int jt=jt0; jt<jt1; ++jt){
        // commit prefetched tile to LDS
        *(uint4*)&Kt[rr][cc]   = pka0;
        *(uint4*)&Kt[rr][cc+8] = pka1;
        *(uint4*)&Vt[rr][cc]   = pva0;
        *(uint4*)&Vt[rr][cc+8] = pva1;
        if (tid < 64){
            kn2s[tid] = pkn;
            l1s[tid]  = pl1;
            akfs[tid] = __builtin_amdgcn_rcpf(fmaxf(1.f - pkn, 1e-6f));
        }
        __syncthreads();
        // issue next tile's global loads (overlap with compute below)
        if (jt+1 < jt1){
            int kv0n = (jt+1) << 6;
            const uint4* gk = (const uint4*)(K + (base + kv0n + rr)*DD + cc);
            pka0 = gk[0]; pka1 = gk[1];
            const uint4* gv = (const uint4*)(VT + ((size_t)bh*DD + rr)*SS + kv0n + cc);
            pva0 = gv[0]; pva1 = gv[1];
            if (tid < 64){ pkn = kn2[base+kv0n+tid]; pl1 = lam1[base+kv0n+tid]; }
        }
        int kv0 = jt << 6;
        // QK^T swapped: c[f][r] = dot(q=l15, k=16f+4l4+r)
        f32x4 c[4] = {z4,z4,z4,z4};
        #pragma unroll
        for (int f=0; f<4; ++f){
            bf16x8 kb0 = *(const bf16x8*)&Kt[f*16+l15][l4*8];
            bf16x8 kb1 = *(const bf16x8*)&Kt[f*16+l15][32+l4*8];
            c[f] = mfma16(kb0, aQ0, c[f]);
            c[f] = mfma16(kb1, aQ1, c[f]);
        }
        // elementwise distance -> w, packed to Wt
        if (jt == qi){
            if (fastw) { EW_BLOCK(true, true) } else { EW_BLOCK(true, false) }
        } else {
            if (fastw) { EW_BLOCK(false, true) } else { EW_BLOCK(false, false) }
        }
        // PV swapped: num[f][r] = M[q=l15][d=16f+4l4+r]
        bf16x8 pw0 = *(const bf16x8*)&Wt[16*wv + l15][l4*8];
        bf16x8 pw1 = *(const bf16x8*)&Wt[16*wv + l15][32 + l4*8];
        #pragma unroll
        for (int f=0; f<4; ++f){
            bf16x8 vb0 = *(const bf16x8*)&Vt[f*16+l15][l4*8];
            bf16x8 vb1 = *(const bf16x8*)&Vt[f*16+l15][32+l4*8];
            num[f] = mfma16(vb0, pw0, num[f]);
            num[f] = mfma16(vb1, pw1, num[f]);
        }
        __syncthreads();
    }
    // den: reduce over the 16 k's held per lane -> over l4 groups
    dn += __shfl_xor(dn, 16, 64);
    dn += __shfl_xor(dn, 32, 64);
    // store partials: pn[q][d] with d-consecutive float4
    size_t pidx = (size_t)bh*144 + offq(qi) + c0;
    float* pn = pnum + pidx*4096;
    #pragma unroll
    for (int f=0; f<4; ++f)
        *(f32x4*)&pn[(16*wv + l15)*64 + f*16 + l4*4] = num[f];
    if (l4 == 0) pden[pidx*64 + 16*wv + l15] = dn;
}

// ---------------- Kernel E: combine partials + gyromidpoint + logmap + expmap --
// block = (b, 16-row s-tile); thread = (row, head, half): tid = row*16 + h*2 + half
__global__ __launch_bounds__(256) void k_post(const float* __restrict__ pnum,
        const float* __restrict__ pden, float* __restrict__ out, float beta){
    int bx = blockIdx.x;              // 2 b x 128 s-tiles
    int b = bx >> 7; int stile = bx & 127;
    int tid = threadIdx.x;
    int row = tid >> 4; int h = (tid >> 1) & 7; int half = tid & 1;
    int s = stile*16 + row;
    int qi = s >> 6; int rowin = s & 63;
    int nch = (qi >> 2) + 1;
    size_t pb = (size_t)(b*HH + h)*144 + offq(qi);
    float mv[32];
    #pragma unroll
    for (int i=0;i<32;++i) mv[i] = 0.f;
    float den = 0.f;
    for (int cc=0; cc<nch; ++cc){
        const float* pn = pnum + (pb+cc)*4096 + rowin*64 + half*32;
        #pragma unroll
        for (int i=0;i<8;++i){
            float4 v = *(const float4*)(pn + i*4);
            mv[i*4+0]+=v.x; mv[i*4+1]+=v.y; mv[i*4+2]+=v.z; mv[i*4+3]+=v.w;
        }
        den += pden[(pb+cc)*64 + rowin];
    }
    float invd = 1.f / fmaxf(den, 1e-6f);
    float mn2h = 0.f;
    #pragma unroll
    for (int i=0;i<32;++i){ mv[i] *= invd; mn2h += mv[i]*mv[i]; }
    // per-head norm over 64 dims: pair (half) reduce
    float mn2 = mn2h + __shfl_xor(mn2h, 1, 64);
    float mn = sqrtf(fmaxf(mn2, 1e-12f));
    float g = beta * 0.5f * fast_atanh(fminf(mn, 1.0f-1e-5f)) / mn;   // t_h = g*m_h
    // E-norm^2 = sum_h g^2*mn2 : reduce over h bits (1,2,3 of tid>>1)
    float tn = g*g*mn2;
    tn += __shfl_xor(tn, 2, 64);
    tn += __shfl_xor(tn, 4, 64);
    tn += __shfl_xor(tn, 8, 64);
    float en = sqrtf(fmaxf(tn, 1e-12f));
    float f = fast_tanh(en)/en;
    float gf = g * f;
    float* dst = out + ((size_t)(b*SS + s))*EE + h*DD + half*32;
    #pragma unroll
    for (int i=0;i<8;++i){
        float4 v = {gf*mv[i*4+0], gf*mv[i*4+1], gf*mv[i*4+2], gf*mv[i*4+3]};
        *(float4*)(dst + i*4) = v;
    }
}

extern "C" void kernel_launch(void* const* d_in, const int* in_sizes, int n_in,
                              void* d_out, int out_size, void* d_ws, size_t ws_size,
                              hipStream_t stream) {
    const float* q_in  = (const float*)d_in[0];
    const float* k_in  = (const float*)d_in[1];
    const float* v_in  = (const float*)d_in[2];
    const float* Wq    = (const float*)d_in[3];
    const float* Wk    = (const float*)d_in[4];
    const float* Wv    = (const float*)d_in[5];
    const float* bq    = (const float*)d_in[6];
    const float* bk    = (const float*)d_in[7];
    const float* bv    = (const float*)d_in[8];
    const float* tau   = (const float*)d_in[9];
    const float* gamma = (const float*)d_in[10];
    float* out = (float*)d_out;

    char* ws = (char*)d_ws;
    u16t*  Tlog = (u16t*)(ws + 0);            // 12,582,912 B
    u16t*  Wb   = (u16t*)(ws + 12582912);     //  1,572,864 B
    u16t*  Ub   = (u16t*)(ws + 14155776);     // 12,582,912 B bf16
    u16t*  Qb   = (u16t*)(ws + 26738688);     //  4,194,304 B
    u16t*  Kb   = (u16t*)(ws + 30932992);     //  4,194,304 B
    u16t*  VTb  = (u16t*)(ws + 35127296);     //  4,194,304 B  (V^T * lambda)
    float* qn2  = (float*)(ws + 39321600);    //    131,072 B
    float* kn2  = (float*)(ws + 39452672);    //    131,072 B
    float* lam1 = (float*)(ws + 39583744);    //    131,072 B
    float* pnum = (float*)(ws + 39714816);    // 16*144*4096*4 = 37,748,736 B
    float* pden = (float*)(ws + 77463552);    // 16*144*64*4   =    589,824 B

    // beta-concatenation ratio: exp(lbeta(E/2,1/2) - lbeta(D/2,1/2))
    double lb1 = std::lgamma(256.0) + std::lgamma(0.5) - std::lgamma(256.5);
    double lb2 = std::lgamma(32.0)  + std::lgamma(0.5) - std::lgamma(32.5);
    float beta = (float)std::exp(lb1 - lb2);

    k_pre<<<3840, 256, 0, stream>>>(q_in, k_in, v_in, Tlog, Wq, Wk, Wv, Wb);
    k_proj<<<1536, 256, 0, stream>>>(Tlog, Wb, bq, bk, bv, Ub);
    k_expmap_split<<<3072, 256, 0, stream>>>(Ub, Qb, Kb, VTb, qn2, kn2, lam1);
    k_attn<<<2304, 256, 0, stream>>>(Qb, Kb, VTb, qn2, kn2, lam1, tau, gamma,
                                     pnum, pden);
    k_post<<<256, 256, 0, stream>>>(pnum, pden, out, beta);
}

// Round 9
// 91.172 us; speedup vs baseline: 1.3287x; 1.0478x over previous
//
#include <hip/hip_runtime.h>
#include <cmath>

#define BB 2
#define SS 2048
#define EE 512
#define HH 8
#define DD 64

typedef unsigned short u16t;
typedef __bf16 bf16x8 __attribute__((ext_vector_type(8)));
typedef float f32x4 __attribute__((ext_vector_type(4)));

__device__ __forceinline__ float bf2f(u16t u){
    union{unsigned int i; float f;} c; c.i = ((unsigned int)u)<<16; return c.f;
}
__device__ __forceinline__ u16t f2bf(float x){
    union{float f; unsigned int i;} c; c.f = x;
    return (u16t)((c.i + 0x7fffu + ((c.i>>16)&1u))>>16);
}
__device__ __forceinline__ unsigned cvtpk(float a, float b){
    unsigned r;
    asm("v_cvt_pk_bf16_f32 %0, %1, %2" : "=v"(r) : "v"(a), "v"(b));
    return r;   // a -> low 16, b -> high 16 (RNE)
}
__device__ __forceinline__ float fast_tanh(float x){
    float e = __expf(2.f*x); return 1.f - 2.f/(e+1.f);
}
__device__ __forceinline__ float fast_atanh(float x){
    return 0.5f*__logf((1.f+x)/(1.f-x));
}
__device__ __forceinline__ f32x4 mfma16(bf16x8 a, bf16x8 b, f32x4 c){
    return __builtin_amdgcn_mfma_f32_16x16x32_bf16(a,b,c,0,0,0);
}
// chunk bookkeeping: QBLK=64, chunk=8 kv-tiles. qi in [0,32):
// nch(qi) = (qi>>3)+1 ; offq8(qi) = sum_{q<qi} nch(q) ; total per bh = 80
__device__ __forceinline__ int offq8(int qi){
    int a = qi >> 3;
    return 4*a*(a+1) + (qi & 7)*(a+1);
}

// ---------------- Kernel A: logmap0 rows (bf16 out) + W cvt, merged ------------
__global__ __launch_bounds__(256) void k_pre(const float* __restrict__ qp,
                                             const float* __restrict__ kp,
                                             const float* __restrict__ vp,
                                             u16t* __restrict__ Tlog,
                                             const float* __restrict__ Wq,
                                             const float* __restrict__ Wk,
                                             const float* __restrict__ Wv,
                                             u16t* __restrict__ Wb){
    int bx = blockIdx.x;
    if (bx < 3072){
        int gr = bx*4 + (threadIdx.x>>6);   // 0..12287
        int t = gr >> 12;
        int row = gr & 4095;
        int lane = threadIdx.x & 63;
        const float* src = (t==0 ? qp : (t==1 ? kp : vp)) + (size_t)row*EE;
        const float4* s4 = (const float4*)(src + lane*8);
        float4 a = s4[0], b = s4[1];
        float x[8] = {a.x,a.y,a.z,a.w,b.x,b.y,b.z,b.w};
        float p = 0.f;
        #pragma unroll
        for (int i=0;i<8;++i) p += x[i]*x[i];
        #pragma unroll
        for (int off=32; off>=1; off>>=1) p += __shfl_xor(p, off, 64);
        float n = sqrtf(fmaxf(p, 1e-12f));
        float f = fast_atanh(fminf(n, 1.0f-1e-5f)) / n;
        u16t yb[8];
        #pragma unroll
        for (int i=0;i<8;++i) yb[i] = f2bf(f*x[i]);
        uint4 o;
        o.x = (unsigned)yb[0] | ((unsigned)yb[1]<<16);
        o.y = (unsigned)yb[2] | ((unsigned)yb[3]<<16);
        o.z = (unsigned)yb[4] | ((unsigned)yb[5]<<16);
        o.w = (unsigned)yb[6] | ((unsigned)yb[7]<<16);
        *(uint4*)(Tlog + ((size_t)(t*4096+row)*EE + lane*8)) = o;
    } else {
        int idx = ((bx-3072)*256 + threadIdx.x)*4;     // 3*512*512 total
        int t = idx >> 18;
        int off = idx & 262143;
        const float* W = (t==0 ? Wq : (t==1 ? Wk : Wv));
        float4 a = *(const float4*)(W + off);
        uint2 o;
        o.x = (unsigned)f2bf(a.x) | ((unsigned)f2bf(a.y)<<16);
        o.y = (unsigned)f2bf(a.z) | ((unsigned)f2bf(a.w)<<16);
        *(uint2*)(Wb + idx) = o;
    }
}

// ---------------- Kernel B: U = Tlog @ W^T + b (MFMA GEMM, bf16 out) -----------
// Swapped operands: D = mfma(W, T) -> lane holds 4 consecutive n-cols per f
// (cvtpk + uint2 stores, float4 bias) instead of 16 scalar stores.
__global__ __launch_bounds__(256) void k_proj(const u16t* __restrict__ Tlog,
                                              const u16t* __restrict__ Wb,
                                              const float* __restrict__ bq,
                                              const float* __restrict__ bk,
                                              const float* __restrict__ bv,
                                              u16t* __restrict__ U){
    __shared__ __align__(16) u16t Wl[64][72];
    int bx = blockIdx.x;                 // 3 * 64 * 8
    int t = bx >> 9; int rem = bx & 511;
    int m0 = (rem >> 3) << 6; int n0 = (rem & 7) << 6;
    int tid = threadIdx.x; int wv = tid>>6; int lane = tid&63;
    int l15 = lane & 15; int l4 = lane >> 4;
    const u16t* Tt = Tlog + (size_t)t*4096*EE;
    const u16t* Wt = Wb + (size_t)t*EE*EE;
    const float* bias = (t==0 ? bq : (t==1 ? bk : bv));
    f32x4 z = {0.f,0.f,0.f,0.f};
    f32x4 acc[4] = {z,z,z,z};
    int arow = m0 + 16*wv + l15;
    int rr = tid >> 2; int cc = (tid & 3) * 16;
    uint4 w0, w1;
    {   // prologue: W-tile ks=0
        const uint4* g = (const uint4*)(Wt + (size_t)(n0+rr)*EE + cc);
        w0 = g[0]; w1 = g[1];
    }
    for (int ks=0; ks<8; ++ks){
        int k0 = ks*64;
        *(uint4*)&Wl[rr][cc]   = w0;
        *(uint4*)&Wl[rr][cc+8] = w1;
        __syncthreads();
        if (ks < 7){
            const uint4* g = (const uint4*)(Wt + (size_t)(n0+rr)*EE + k0 + 64 + cc);
            w0 = g[0]; w1 = g[1];
        }
        bf16x8 a0 = *(const bf16x8*)(Tt + (size_t)arow*EE + k0 + l4*8);
        bf16x8 a1 = *(const bf16x8*)(Tt + (size_t)arow*EE + k0 + 32 + l4*8);
        #pragma unroll
        for (int f=0; f<4; ++f){
            bf16x8 b0 = *(const bf16x8*)&Wl[f*16+l15][l4*8];
            bf16x8 b1 = *(const bf16x8*)&Wl[f*16+l15][32+l4*8];
            acc[f] = mfma16(b0, a0, acc[f]);   // swapped: rows=n, cols=m
            acc[f] = mfma16(b1, a1, acc[f]);
        }
        __syncthreads();
    }
    u16t* Ut = U + (size_t)t*4096*EE;
    int mrow = m0 + 16*wv + l15;
    #pragma unroll
    for (int f=0; f<4; ++f){
        float4 b4 = *(const float4*)&bias[n0 + f*16 + l4*4];
        uint2 u2;
        u2.x = cvtpk(acc[f][0]+b4.x, acc[f][1]+b4.y);
        u2.y = cvtpk(acc[f][2]+b4.z, acc[f][3]+b4.w);
        *(uint2*)(Ut + (size_t)mrow*EE + n0 + f*16 + l4*4) = u2;
    }
}

// ---------------- Kernel C: expmap0 + head split + norms (V stored transposed) --
__global__ __launch_bounds__(256) void k_expmap_split(const u16t* __restrict__ U,
        u16t* __restrict__ Q, u16t* __restrict__ K, u16t* __restrict__ VT,
        float* __restrict__ qn2, float* __restrict__ kn2, float* __restrict__ lam1){
    int gr = blockIdx.x*4 + (threadIdx.x>>6);   // 0..12287
    int t = gr >> 12;
    int row = gr & 4095;
    int b = row >> 11; int s = row & 2047;
    int lane = threadIdx.x & 63;
    const u16t* u = U + ((size_t)t*4096 + row)*EE;
    uint4 raw = *(const uint4*)(u + lane*8);
    const u16t* rs = (const u16t*)&raw;
    float x[8];
    #pragma unroll
    for (int i=0;i<8;++i) x[i] = bf2f(rs[i]);
    float p = 0.f;
    #pragma unroll
    for (int i=0;i<8;++i) p += x[i]*x[i];
    #pragma unroll
    for (int off=32; off>=1; off>>=1) p += __shfl_xor(p, off, 64);
    float n = sqrtf(fmaxf(p, 1e-12f));
    float f = fast_tanh(n)/n;
    float y[8]; u16t yb[8];
    float hp = 0.f;
    #pragma unroll
    for (int i=0;i<8;++i){
        yb[i] = f2bf(f*x[i]);
        y[i]  = bf2f(yb[i]);        // rounded values -> consistent norms
        hp += y[i]*y[i];
    }
    #pragma unroll
    for (int off=1; off<8; off<<=1) hp += __shfl_xor(hp, off, 64);
    hp = fminf(hp, 0.99999988f);    // guard: keep strictly below 1 for rcp path
    int h = lane >> 3;
    size_t ih = (size_t)(b*HH + h)*SS + s;
    if (t == 0){
        uint4 o;
        o.x=(unsigned)yb[0]|((unsigned)yb[1]<<16); o.y=(unsigned)yb[2]|((unsigned)yb[3]<<16);
        o.z=(unsigned)yb[4]|((unsigned)yb[5]<<16); o.w=(unsigned)yb[6]|((unsigned)yb[7]<<16);
        *(uint4*)(Q + ih*DD + (lane&7)*8) = o;
        if ((lane&7)==0) qn2[ih] = hp;
    } else if (t == 1){
        uint4 o;
        o.x=(unsigned)yb[0]|((unsigned)yb[1]<<16); o.y=(unsigned)yb[2]|((unsigned)yb[3]<<16);
        o.z=(unsigned)yb[4]|((unsigned)yb[5]<<16); o.w=(unsigned)yb[6]|((unsigned)yb[7]<<16);
        *(uint4*)(K + ih*DD + (lane&7)*8) = o;
        if ((lane&7)==0) kn2[ih] = hp;
    } else {
        float lam = 2.f / fmaxf(1.f - hp, 1e-6f);
        size_t bh = (size_t)(b*HH + h);
        int d0 = (lane&7)*8;
        #pragma unroll
        for (int i=0;i<8;++i)
            VT[(bh*DD + d0 + i)*SS + s] = f2bf(y[i]*lam);   // V^T, scaled by lambda
        if ((lane&7)==0) lam1[ih] = lam - 1.f;
    }
}

// ---------------- Kernel D: fused causal hyperbolic attention ------------------
// QBLK=64 (4 waves x 16q), KVBLK=64, chunk=8. Swapped-operand MFMAs; w packed
// via v_cvt_pk_bf16_f32; fast path w=rcp(zz) when tau'==1 && gamma==0 (exact:
// exp(-1*dist+0) == 1/zz), general log/exp path otherwise.
#define EW_BLOCK(DO_DIAG, FASTW)                                              \
    _Pragma("unroll")                                                         \
    for (int f=0; f<4; ++f){                                                  \
        float4 kn24 = *(const float4*)&kn2s[f*16 + l4*4];                     \
        float4 akf4 = *(const float4*)&akfs[f*16 + l4*4];                     \
        float4 l14  = *(const float4*)&l1s [f*16 + l4*4];                     \
        float wv4[4];                                                         \
        _Pragma("unroll")                                                     \
        for (int r=0; r<4; ++r){                                              \
            float sq  = fmaxf(fmaf(-2.f, c[f][r], qv + ((const float*)&kn24)[r]), 0.f); \
            float co  = fminf(aq2 * ((const float*)&akf4)[r], 2e6f);          \
            float rho = sq * co;                                              \
            float tt  = fmaf(rho, rho, rho + rho);                            \
            float zz  = 1.f + rho + __builtin_amdgcn_sqrtf(tt);               \
            float w;                                                          \
            if (FASTW){ w = __builtin_amdgcn_rcpf(zz); }                      \
            else { float L = __builtin_amdgcn_logf(zz);                       \
                   w = __builtin_amdgcn_exp2f(fmaf(-tauexp, L, gm2)); }       \
            if (DO_DIAG && (kv0 + f*16 + l4*4 + r) > qrow) w = 0.f;           \
            dn = fmaf(w, ((const float*)&l14)[r], dn);                        \
            wv4[r] = w;                                                       \
        }                                                                     \
        uint2 u2; u2.x = cvtpk(wv4[0], wv4[1]); u2.y = cvtpk(wv4[2], wv4[3]); \
        *(uint2*)&Wt[16*wv + l15][f*16 + l4*4] = u2;                          \
    }

__global__ __launch_bounds__(256,5) void k_attn(const u16t* __restrict__ Q,
        const u16t* __restrict__ K, const u16t* __restrict__ VT,
        const float* __restrict__ qn2, const float* __restrict__ kn2,
        const float* __restrict__ lam1, const float* __restrict__ taup,
        const float* __restrict__ gammap,
        float* __restrict__ pnum, float* __restrict__ pden){
    __shared__ __align__(16) u16t Kt[64][72];
    __shared__ __align__(16) u16t Vt[64][72];   // V^T tile: [d][kv]
    __shared__ __align__(16) u16t Wt[64][72];   // w[q][kv], per-wave row stripes
    __shared__ float kn2s[64], akfs[64], l1s[64];
    int bx = blockIdx.x;
    int bh = bx & 15;               // low bits -> per-bh XCD/L2 affinity
    int u = bx >> 4;                // 0..79
    int v = 79 - u;                 // heavy qi first
    int qi = 31;
    while (offq8(qi) > v) --qi;
    int c0 = v - offq8(qi);
    int jt0 = c0 << 3;
    int jt1 = min(jt0 + 8, qi + 1);
    int s0 = qi << 6;
    int tid = threadIdx.x; int wv = tid>>6; int lane = tid&63;
    int l15 = lane & 15; int l4 = lane >> 4;
    float tauexp = __expf(taup[0]);
    float gm2 = gammap[0] * 1.44269504088896340736f;  // gamma * log2(e)
    bool fastw = (tauexp == 1.0f) && (gm2 == 0.0f);
    size_t base = (size_t)bh * SS;
    int qrow = s0 + 16*wv + l15;    // this lane's global q row
    bf16x8 aQ0 = *(const bf16x8*)(Q + (base + qrow)*DD + l4*8);
    bf16x8 aQ1 = *(const bf16x8*)(Q + (base + qrow)*DD + 32 + l4*8);
    float qv  = qn2[base + qrow];
    float aq2 = 2.f * __builtin_amdgcn_rcpf(fmaxf(1.f - qv, 1e-6f));
    f32x4 z4 = {0.f,0.f,0.f,0.f};
    f32x4 num[4] = {z4,z4,z4,z4};
    float dn = 0.f;
    int rr = tid >> 2; int cc = (tid & 3) << 4;
    // register prefetch (T14)
    uint4 pka0, pka1, pva0, pva1; float pkn = 0.f, pl1 = 0.f;
    {   // prologue: load tile jt0
        int kv0 = jt0 << 6;
        const uint4* gk = (const uint4*)(K + (base + kv0 + rr)*DD + cc);
        pka0 = gk[0]; pka1 = gk[1];
        const uint4* gv = (const uint4*)(VT + ((size_t)bh*DD + rr)*SS + kv0 + cc);
        pva0 = gv[0]; pva1 = gv[1];
        if (tid < 64){ pkn = kn2[base+kv0+tid]; pl1 = lam1[base+kv0+tid]; }
    }
    for (int jt=jt0; jt<jt1; ++jt){
        // commit prefetched tile to LDS
        *(uint4*)&Kt[rr][cc]   = pka0;
        *(uint4*)&Kt[rr][cc+8] = pka1;
        *(uint4*)&Vt[rr][cc]   = pva0;
        *(uint4*)&Vt[rr][cc+8] = pva1;
        if (tid < 64){
            kn2s[tid] = pkn;
            l1s[tid]  = pl1;
            akfs[tid] = __builtin_amdgcn_rcpf(fmaxf(1.f - pkn, 1e-6f));
        }
        __syncthreads();
        // issue next tile's global loads (overlap with compute below)
        if (jt+1 < jt1){
            int kv0n = (jt+1) << 6;
            const uint4* gk = (const uint4*)(K + (base + kv0n + rr)*DD + cc);
            pka0 = gk[0]; pka1 = gk[1];
            const uint4* gv = (const uint4*)(VT + ((size_t)bh*DD + rr)*SS + kv0n + cc);
            pva0 = gv[0]; pva1 = gv[1];
            if (tid < 64){ pkn = kn2[base+kv0n+tid]; pl1 = lam1[base+kv0n+tid]; }
        }
        int kv0 = jt << 6;
        // QK^T swapped: c[f][r] = dot(q=l15, k=16f+4l4+r)
        f32x4 c[4] = {z4,z4,z4,z4};
        #pragma unroll
        for (int f=0; f<4; ++f){
            bf16x8 kb0 = *(const bf16x8*)&Kt[f*16+l15][l4*8];
            bf16x8 kb1 = *(const bf16x8*)&Kt[f*16+l15][32+l4*8];
            c[f] = mfma16(kb0, aQ0, c[f]);
            c[f] = mfma16(kb1, aQ1, c[f]);
        }
        // elementwise distance -> w, packed to Wt
        if (jt == qi){
            if (fastw) { EW_BLOCK(true, true) } else { EW_BLOCK(true, false) }
        } else {
            if (fastw) { EW_BLOCK(false, true) } else { EW_BLOCK(false, false) }
        }
        // PV swapped: num[f][r] = M[q=l15][d=16f+4l4+r]
        bf16x8 pw0 = *(const bf16x8*)&Wt[16*wv + l15][l4*8];
        bf16x8 pw1 = *(const bf16x8*)&Wt[16*wv + l15][32 + l4*8];
        #pragma unroll
        for (int f=0; f<4; ++f){
            bf16x8 vb0 = *(const bf16x8*)&Vt[f*16+l15][l4*8];
            bf16x8 vb1 = *(const bf16x8*)&Vt[f*16+l15][32+l4*8];
            num[f] = mfma16(vb0, pw0, num[f]);
            num[f] = mfma16(vb1, pw1, num[f]);
        }
        __syncthreads();
    }
    // den: reduce over the 16 k's held per lane -> over l4 groups
    dn += __shfl_xor(dn, 16, 64);
    dn += __shfl_xor(dn, 32, 64);
    // store partials: pn[q][d] with d-consecutive float4
    size_t pidx = (size_t)bh*80 + offq8(qi) + c0;
    float* pn = pnum + pidx*4096;
    #pragma unroll
    for (int f=0; f<4; ++f)
        *(f32x4*)&pn[(16*wv + l15)*64 + f*16 + l4*4] = num[f];
    if (l4 == 0) pden[pidx*64 + 16*wv + l15] = dn;
}

// ---------------- Kernel E: combine partials + gyromidpoint + logmap + expmap --
// block = (b, 16-row s-tile); thread = (row, head, half): tid = row*16 + h*2 + half
__global__ __launch_bounds__(256) void k_post(const float* __restrict__ pnum,
        const float* __restrict__ pden, float* __restrict__ out, float beta){
    int bx = blockIdx.x;              // 2 b x 128 s-tiles
    int b = bx >> 7; int stile = bx & 127;
    int tid = threadIdx.x;
    int row = tid >> 4; int h = (tid >> 1) & 7; int half = tid & 1;
    int s = stile*16 + row;
    int qi = s >> 6; int rowin = s & 63;
    int nch = (qi >> 3) + 1;
    size_t pb = (size_t)(b*HH + h)*80 + offq8(qi);
    float mv[32];
    #pragma unroll
    for (int i=0;i<32;++i) mv[i] = 0.f;
    float den = 0.f;
    for (int cc=0; cc<nch; ++cc){
        const float* pn = pnum + (pb+cc)*4096 + rowin*64 + half*32;
        #pragma unroll
        for (int i=0;i<8;++i){
            float4 v = *(const float4*)(pn + i*4);
            mv[i*4+0]+=v.x; mv[i*4+1]+=v.y; mv[i*4+2]+=v.z; mv[i*4+3]+=v.w;
        }
        den += pden[(pb+cc)*64 + rowin];
    }
    float invd = 1.f / fmaxf(den, 1e-6f);
    float mn2h = 0.f;
    #pragma unroll
    for (int i=0;i<32;++i){ mv[i] *= invd; mn2h += mv[i]*mv[i]; }
    // per-head norm over 64 dims: pair (half) reduce
    float mn2 = mn2h + __shfl_xor(mn2h, 1, 64);
    float mn = sqrtf(fmaxf(mn2, 1e-12f));
    float g = beta * 0.5f * fast_atanh(fminf(mn, 1.0f-1e-5f)) / mn;   // t_h = g*m_h
    // E-norm^2 = sum_h g^2*mn2 : reduce over h bits (1,2,3 of tid>>1)
    float tn = g*g*mn2;
    tn += __shfl_xor(tn, 2, 64);
    tn += __shfl_xor(tn, 4, 64);
    tn += __shfl_xor(tn, 8, 64);
    float en = sqrtf(fmaxf(tn, 1e-12f));
    float f = fast_tanh(en)/en;
    float gf = g * f;
    float* dst = out + ((size_t)(b*SS + s))*EE + h*DD + half*32;
    #pragma unroll
    for (int i=0;i<8;++i){
        float4 v = {gf*mv[i*4+0], gf*mv[i*4+1], gf*mv[i*4+2], gf*mv[i*4+3]};
        *(float4*)(dst + i*4) = v;
    }
}

extern "C" void kernel_launch(void* const* d_in, const int* in_sizes, int n_in,
                              void* d_out, int out_size, void* d_ws, size_t ws_size,
                              hipStream_t stream) {
    const float* q_in  = (const float*)d_in[0];
    const float* k_in  = (const float*)d_in[1];
    const float* v_in  = (const float*)d_in[2];
    const float* Wq    = (const float*)d_in[3];
    const float* Wk    = (const float*)d_in[4];
    const float* Wv    = (const float*)d_in[5];
    const float* bq    = (const float*)d_in[6];
    const float* bk    = (const float*)d_in[7];
    const float* bv    = (const float*)d_in[8];
    const float* tau   = (const float*)d_in[9];
    const float* gamma = (const float*)d_in[10];
    float* out = (float*)d_out;

    char* ws = (char*)d_ws;
    u16t*  Tlog = (u16t*)(ws + 0);            // 12,582,912 B
    u16t*  Wb   = (u16t*)(ws + 12582912);     //  1,572,864 B
    u16t*  Ub   = (u16t*)(ws + 14155776);     // 12,582,912 B bf16
    u16t*  Qb   = (u16t*)(ws + 26738688);     //  4,194,304 B
    u16t*  Kb   = (u16t*)(ws + 30932992);     //  4,194,304 B
    u16t*  VTb  = (u16t*)(ws + 35127296);     //  4,194,304 B  (V^T * lambda)
    float* qn2  = (float*)(ws + 39321600);    //    131,072 B
    float* kn2  = (float*)(ws + 39452672);    //    131,072 B
    float* lam1 = (float*)(ws + 39583744);    //    131,072 B
    float* pnum = (float*)(ws + 39714816);    // 16*80*4096*4 = 20,971,520 B
    float* pden = (float*)(ws + 60686336);    // 16*80*64*4   =    327,680 B

    // beta-concatenation ratio: exp(lbeta(E/2,1/2) - lbeta(D/2,1/2))
    double lb1 = std::lgamma(256.0) + std::lgamma(0.5) - std::lgamma(256.5);
    double lb2 = std::lgamma(32.0)  + std::lgamma(0.5) - std::lgamma(32.5);
    float beta = (float)std::exp(lb1 - lb2);

    k_pre<<<3840, 256, 0, stream>>>(q_in, k_in, v_in, Tlog, Wq, Wk, Wv, Wb);
    k_proj<<<1536, 256, 0, stream>>>(Tlog, Wb, bq, bk, bv, Ub);
    k_expmap_split<<<3072, 256, 0, stream>>>(Ub, Qb, Kb, VTb, qn2, kn2, lam1);
    k_attn<<<1280, 256, 0, stream>>>(Qb, Kb, VTb, qn2, kn2, lam1, tau, gamma,
                                     pnum, pden);
    k_post<<<256, 256, 0, stream>>>(pnum, pden, out, beta);
}